// Round 10
// baseline (179.920 us; speedup 1.0000x reference)
//
#include <hip/hip_runtime.h>
#include <math.h>

// Dims (fixed by the reference)
#define B_   2048
#define C_   64
#define H_   768
#define NC_  1000
#define H2_  384   // H/2
#define H4_  192   // H/4
#define RIN_ 960   // H + H/4

using short8 = __attribute__((ext_vector_type(8))) short;
using f32x4  = __attribute__((ext_vector_type(4))) float;

__device__ __forceinline__ float silu_(float x){
    float e = __expf(-x);
    return x * __fdividef(1.f, 1.f + e);
}
// round-to-nearest-even f32 -> bf16
__device__ __forceinline__ unsigned short f2bf_(float x){
    unsigned int u = __float_as_uint(x);
    u += 0x7fffu + ((u >> 16) & 1u);
    return (unsigned short)(u >> 16);
}
// truncating f32 -> bf16 (for lo residuals; residual-of-residual < 2^-17)
__device__ __forceinline__ unsigned short f2bft_(float x){
    return (unsigned short)(__float_as_uint(x) >> 16);
}
__device__ __forceinline__ float bf2f_(unsigned short h){
    return __uint_as_float(((unsigned int)h) << 16);
}

__global__ void k_sentinel(float* __restrict__ out, float code){ out[0] = code; }

// ---------------------------------------------------------------------------
// K-prep (fused): blockIdx dispatch
//   [0,1152)    : split w1 (768x384) -> chunk-major bf16 hi/lo
//   [1152,1440) : split w2 (384x192) -> chunk-major bf16 hi/lo
//   [1440,2440) : E1[id] = emb[id] @ w1[768:960]
//   [2440]      : int64-vs-int32 detector on ids
// ---------------------------------------------------------------------------
#define PREP_W1E_ 1152
#define PREP_W2E_ 1440
#define PREP_E1E_ 2440
__global__ __launch_bounds__(256) void k_prep(const float* __restrict__ w1,
                                              const float* __restrict__ w2,
                                              const float* __restrict__ emb,
                                              const int*   __restrict__ ids32,
                                              unsigned short* __restrict__ w1hi,
                                              unsigned short* __restrict__ w1lo,
                                              unsigned short* __restrict__ w2hi,
                                              unsigned short* __restrict__ w2lo,
                                              float* __restrict__ E1,
                                              int* __restrict__ flag)
{
    __shared__ float er[H4_];
    __shared__ int any_nz;
    const int bb = blockIdx.x, t = threadIdx.x;

    if (bb < PREP_W1E_) {
        const int idx = bb * 256 + t;                  // < 768*384 exactly
        const int k = idx / H2_, j = idx - k * H2_;
        float x = w1[idx];
        unsigned short h = f2bf_(x);
        size_t dst = (size_t)(k >> 5) * (H2_ * 32) + (size_t)j * 32 + (k & 31);
        w1hi[dst] = h;
        w1lo[dst] = f2bft_(x - bf2f_(h));
    } else if (bb < PREP_W2E_) {
        const int idx = (bb - PREP_W1E_) * 256 + t;    // < 384*192 exactly
        const int k = idx / H4_, j = idx - k * H4_;
        float x = w2[idx];
        unsigned short h = f2bf_(x);
        size_t dst = (size_t)(k >> 5) * (H4_ * 32) + (size_t)j * 32 + (k & 31);
        w2hi[dst] = h;
        w2lo[dst] = f2bft_(x - bf2f_(h));
    } else if (bb < PREP_E1E_) {
        const int id = bb - PREP_W2E_;
        if (t < H4_) er[t] = emb[id * H4_ + t];
        __syncthreads();
        for (int k = t; k < H2_; k += 256) {
            float acc = 0.f;
            const float* wc = w1 + (size_t)H_ * H2_ + k;
            #pragma unroll 8
            for (int r = 0; r < H4_; ++r) acc += er[r] * wc[(size_t)r * H2_];
            E1[id * H2_ + k] = acc;
        }
    } else {
        if (t == 0) any_nz = 0;
        __syncthreads();
        int local = 0;
        for (int i = t; i < 2048; i += 256)
            if (ids32[2 * i + 1] != 0) { local = 1; break; }
        if (local) atomicOr(&any_nz, 1);
        __syncthreads();
        if (t == 0) flag[0] = (any_nz == 0) ? 1 : 0;
    }
}

// ---------------------------------------------------------------------------
// K2: T1 = te @ w1[:768] + b1 via MFMA bf16x3. te split in-register.
// grid (B/16, 4), 128 threads = 2 waves; wave owns 48 cols (3 j-tiles).
// ---------------------------------------------------------------------------
__global__ __launch_bounds__(128) void k_t1_mfma(const float* __restrict__ te,
                                                 const unsigned short* __restrict__ w1hi,
                                                 const unsigned short* __restrict__ w1lo,
                                                 const float* __restrict__ b1,
                                                 float* __restrict__ T1)
{
    const int b0 = blockIdx.x * 16;
    const int jb = blockIdx.y * 96;
    const int t = threadIdx.x, w = t >> 6, l = t & 63;
    const int m = l & 15, g = l >> 4;
    const int row = b0 + m;

    f32x4 acc[3];
    #pragma unroll
    for (int jt = 0; jt < 3; ++jt) acc[jt] = (f32x4){0.f, 0.f, 0.f, 0.f};

    for (int ck = 0; ck < 24; ++ck) {
        const int kk = ck * 32;
        const float* pa = te + (size_t)row * H_ + kk + g * 8;
        float4 a0 = *(const float4*)pa;
        float4 a1 = *(const float4*)(pa + 4);
        float av[8] = {a0.x, a0.y, a0.z, a0.w, a1.x, a1.y, a1.z, a1.w};
        short8 ahi, alo;
        #pragma unroll
        for (int i = 0; i < 8; ++i) {
            unsigned short h = f2bf_(av[i]);
            ahi[i] = (short)h;
            alo[i] = (short)f2bft_(av[i] - bf2f_(h));
        }
        #pragma unroll
        for (int jt = 0; jt < 3; ++jt) {
            const int j = jb + w * 48 + jt * 16 + m;
            const size_t o = (size_t)ck * (H2_ * 32) + (size_t)j * 32 + g * 8;
            short8 bhi = *(const short8*)&w1hi[o];
            short8 blo = *(const short8*)&w1lo[o];
            acc[jt] = __builtin_amdgcn_mfma_f32_16x16x32_bf16(ahi, bhi, acc[jt], 0, 0, 0);
            acc[jt] = __builtin_amdgcn_mfma_f32_16x16x32_bf16(ahi, blo, acc[jt], 0, 0, 0);
            acc[jt] = __builtin_amdgcn_mfma_f32_16x16x32_bf16(alo, bhi, acc[jt], 0, 0, 0);
        }
    }

    #pragma unroll
    for (int jt = 0; jt < 3; ++jt) {
        const int j = jb + w * 48 + jt * 16 + m;
        const float bj = b1[j];
        #pragma unroll
        for (int reg = 0; reg < 4; ++reg)
            T1[(size_t)(b0 + g * 4 + reg) * H2_ + j] = acc[jt][reg] + bj;
    }
}

// ---------------------------------------------------------------------------
// K3: producer/consumer MFMA kernel. One block per task, 512 threads = 8 waves:
//   waves 0..5 consumers (32 j-cols each: 2 jt x 4 rt x 3 = 24 MFMA/chunk),
//   waves 6..7 producers (stage h1 chunk ck+1: silu+bf16-split into LDS dbuf).
//   One barrier per chunk; producer staging genuinely overlaps consumer MFMA.
// LDS: 20 (h1 dbuf) + 1.5 (T1b) + 1.5 (b2/w3) + 0.5 (ids/lab) + 3 (sred) = 26.5 KB
// ---------------------------------------------------------------------------
#define HS_   40          // h1 LDS row stride in ushorts
#define CONS_ 6           // consumer waves
__global__ __launch_bounds__(512, 4) void k_main(const float* __restrict__ T1,
                                                 const float* __restrict__ E1,
                                                 const int*   __restrict__ ids,
                                                 const int*   __restrict__ labels,
                                                 const unsigned short* __restrict__ w2hi,
                                                 const unsigned short* __restrict__ w2lo,
                                                 const float* __restrict__ b2,
                                                 const float* __restrict__ w3,
                                                 const float* __restrict__ b3,
                                                 const float* __restrict__ cbias,
                                                 const int*   __restrict__ iflag,
                                                 float* __restrict__ out)
{
    __shared__ __align__(16) unsigned short h1hiS[2][C_ * HS_];  // 10 KB
    __shared__ __align__(16) unsigned short h1loS[2][C_ * HS_];  // 10 KB
    __shared__ __align__(16) float T1b[H2_];
    __shared__ float b2S[H4_], w3S[H4_];
    __shared__ int   ids_s[C_], lab_s[C_];
    __shared__ double sredS[CONS_ * C_];                         // 3 KB

    const int b = blockIdx.x;
    const int t = threadIdx.x;
    const int l = t & 63, w = t >> 6;
    const int m = l & 15, g = l >> 4;
    const int kq0 = g * 8;

    if (t < C_) {
        if (iflag[0]) {
            ids_s[t] = (int)((const long long*)ids)[(size_t)b * C_ + t];
            lab_s[t] = (int)((const long long*)labels)[(size_t)b * C_ + t];
        } else {
            ids_s[t] = ids[b * C_ + t];
            lab_s[t] = labels[b * C_ + t];
        }
    }
    if (t < H2_) T1b[t] = T1[(size_t)b * H2_ + t];
    if (t < H4_) { b2S[t] = b2[t]; w3S[t] = w3[t]; }

    // producer staging: chunk ck -> buffer buf (128 producer lanes, 16 elems each)
    auto STAGE = [&](int ck, int buf) {
        const int kk = ck * 32;
        const int p = t - CONS_ * 64;        // 0..127
        #pragma unroll
        for (int it = 0; it < 4; ++it) {
            const int i  = p + it * 128;     // 0..511
            const int c  = i >> 3;
            const int kq = i & 7;
            float4 e  = *(const float4*)&E1[(size_t)ids_s[c] * H2_ + kk + kq * 4];
            float4 tv = *(const float4*)&T1b[kk + kq * 4];
            float x0 = silu_(tv.x + e.x), x1 = silu_(tv.y + e.y);
            float x2 = silu_(tv.z + e.z), x3 = silu_(tv.w + e.w);
            unsigned short h0 = f2bf_(x0), h1v = f2bf_(x1), h2v = f2bf_(x2), h3 = f2bf_(x3);
            uint2 uh, ul;
            uh.x = (unsigned)h0 | ((unsigned)h1v << 16);
            uh.y = (unsigned)h2v | ((unsigned)h3 << 16);
            ul.x = (unsigned)f2bft_(x0 - bf2f_(h0)) | ((unsigned)f2bft_(x1 - bf2f_(h1v)) << 16);
            ul.y = (unsigned)f2bft_(x2 - bf2f_(h2v)) | ((unsigned)f2bft_(x3 - bf2f_(h3)) << 16);
            *(uint2*)&h1hiS[buf][c * HS_ + kq * 4] = uh;
            *(uint2*)&h1loS[buf][c * HS_ + kq * 4] = ul;
        }
    };

    __syncthreads();                 // T1b / ids_s ready
    if (w >= CONS_) STAGE(0, 0);
    __syncthreads();                 // buf0 staged

    f32x4 acc[4][2];
    #pragma unroll
    for (int rt = 0; rt < 4; ++rt)
        #pragma unroll
        for (int jt = 0; jt < 2; ++jt) acc[rt][jt] = (f32x4){0.f, 0.f, 0.f, 0.f};

    for (int ck = 0; ck < 12; ++ck) {
        const int cur = ck & 1;
        if (w < CONS_) {
            const unsigned short* gbh = w2hi + (size_t)ck * (H4_ * 32);
            const unsigned short* gbl = w2lo + (size_t)ck * (H4_ * 32);
            short8 bhi[2], blo[2];
            #pragma unroll
            for (int jt = 0; jt < 2; ++jt) {
                const int j = 32 * w + jt * 16 + m;
                bhi[jt] = *(const short8*)&gbh[j * 32 + kq0];
                blo[jt] = *(const short8*)&gbl[j * 32 + kq0];
            }
            short8 ahi[4], alo[4];
            #pragma unroll
            for (int rt = 0; rt < 4; ++rt) {
                ahi[rt] = *(const short8*)&h1hiS[cur][(rt * 16 + m) * HS_ + kq0];
                alo[rt] = *(const short8*)&h1loS[cur][(rt * 16 + m) * HS_ + kq0];
            }
            #pragma unroll
            for (int jt = 0; jt < 2; ++jt)
                #pragma unroll
                for (int rt = 0; rt < 4; ++rt) {
                    acc[rt][jt] = __builtin_amdgcn_mfma_f32_16x16x32_bf16(ahi[rt], bhi[jt], acc[rt][jt], 0, 0, 0);
                    acc[rt][jt] = __builtin_amdgcn_mfma_f32_16x16x32_bf16(ahi[rt], blo[jt], acc[rt][jt], 0, 0, 0);
                    acc[rt][jt] = __builtin_amdgcn_mfma_f32_16x16x32_bf16(alo[rt], bhi[jt], acc[rt][jt], 0, 0, 0);
                }
        } else {
            if (ck + 1 < 12) STAGE(ck + 1, cur ^ 1);
        }
        __syncthreads();
    }

    // epilogue: consumers compute p-sums in f64, reduce over 16 cols, stash
    if (w < CONS_) {
        double p[4][4];
        #pragma unroll
        for (int rt = 0; rt < 4; ++rt)
            #pragma unroll
            for (int reg = 0; reg < 4; ++reg) p[rt][reg] = 0.0;
        #pragma unroll
        for (int jt = 0; jt < 2; ++jt) {
            const int j = 32 * w + jt * 16 + m;
            const float bj = b2S[j];
            const double w3j = (double)w3S[j];
            #pragma unroll
            for (int rt = 0; rt < 4; ++rt)
                #pragma unroll
                for (int reg = 0; reg < 4; ++reg)
                    p[rt][reg] += (double)silu_(acc[rt][jt][reg] + bj) * w3j;
        }
        #pragma unroll
        for (int rt = 0; rt < 4; ++rt)
            #pragma unroll
            for (int reg = 0; reg < 4; ++reg) {
                double v = p[rt][reg];
                v += __shfl_xor(v, 1);
                v += __shfl_xor(v, 2);
                v += __shfl_xor(v, 4);
                v += __shfl_xor(v, 8);
                p[rt][reg] = v;
            }
        if (m == 0) {
            #pragma unroll
            for (int rt = 0; rt < 4; ++rt)
                #pragma unroll
                for (int reg = 0; reg < 4; ++reg)
                    sredS[w * C_ + rt * 16 + g * 4 + reg] = p[rt][reg];
        }
    }
    __syncthreads();

    if (t < C_) {
        const int c = t;
        double s = 0.0;
        #pragma unroll
        for (int gg = 0; gg < CONS_; ++gg) s += sredS[gg * C_ + c];
        double est = 1.0 / (1.0 + exp(-(s + (double)b3[0])));
        double rel = 1.0 / (1.0 + exp(-(est + (double)cbias[ids_s[c]])));
        out[B_ + (size_t)b * C_ + c] = (float)rel;

        const int lb = lab_s[c];
        double mg = (lb == 1) ? rel : ((lb == 0) ? -rel : 0.0);
        #pragma unroll
        for (int o = 32; o > 0; o >>= 1) mg += __shfl_down(mg, o);
        if (t == 0) out[b] = (mg > 0.0) ? 1.0f : 0.0f;
    }
}

// ---------------------------------------------------------------------------
extern "C" void kernel_launch(void* const* d_in, const int* in_sizes, int n_in,
                              void* d_out, int out_size, void* d_ws, size_t ws_size,
                              hipStream_t stream)
{
    const float* te    = (const float*)d_in[0];
    const int*   ids   = (const int*)  d_in[1];
    const int*   labs  = (const int*)  d_in[2];
    const float* w1    = (const float*)d_in[3];
    const float* b1    = (const float*)d_in[4];
    const float* w2    = (const float*)d_in[5];
    const float* b2    = (const float*)d_in[6];
    const float* w3    = (const float*)d_in[7];
    const float* b3    = (const float*)d_in[8];
    const float* cbias = (const float*)d_in[14];
    const float* emb   = (const float*)d_in[13];
    float* out = (float*)d_out;

    const int expect[15] = {B_*H_, B_*C_, B_*C_, RIN_*H2_, H2_, H2_*H4_, H4_,
                            H4_, 1, H_*H2_, H2_, H2_, 1, NC_*H4_, NC_};
    if (n_in != 15) {
        k_sentinel<<<1, 1, 0, stream>>>(out, 3000.0f + (float)n_in);
        return;
    }
    for (int i = 0; i < 15; ++i) {
        if (in_sizes[i] != expect[i]) {
            k_sentinel<<<1, 1, 0, stream>>>(out, 2000.0f + 10.0f * (float)i);
            return;
        }
    }

    // ws layout: E1 f32 | T1 f32 | w1s hi/lo u16 | w2s hi/lo u16 | iflag
    const size_t nE1 = (size_t)NC_ * H2_;
    const size_t nT1 = (size_t)B_ * H2_;
    const size_t nW1 = (size_t)RIN_ * H2_;
    const size_t nW2 = (size_t)H2_ * H4_;
    const size_t need = nE1 * 4 + nT1 * 4 + nW1 * 2 * 2 + nW2 * 2 * 2 + 16;
    if (ws_size < need) {
        k_sentinel<<<1, 1, 0, stream>>>(out, 1000.0f + (float)((double)ws_size / (1024.0 * 1024.0)));
        return;
    }
    float* ws = (float*)d_ws;
    float* E1 = ws;
    float* T1 = E1 + nE1;
    unsigned short* w1hi = (unsigned short*)(T1 + nT1);
    unsigned short* w1lo = w1hi + nW1;
    unsigned short* w2hi = w1lo + nW1;
    unsigned short* w2lo = w2hi + nW2;
    int* iflag = (int*)(w2lo + nW2);

    k_prep<<<PREP_E1E_ + 1, 256, 0, stream>>>(w1, w2, emb, ids,
                                              w1hi, w1lo, w2hi, w2lo, E1, iflag);
    k_t1_mfma<<<dim3(B_ / 16, 4), 128, 0, stream>>>(te, w1hi, w1lo, b1, T1);
    k_main<<<B_, 512, 0, stream>>>(T1, E1, ids, labs, w2hi, w2lo, b2, w3, b3, cbias, iflag, out);
}